// Round 1
// baseline (125.718 us; speedup 1.0000x reference)
//
#include <hip/hip_runtime.h>
#include <hip/hip_bf16.h>
#include <math.h>

typedef __bf16 bf16;
typedef __bf16 bf16x8 __attribute__((ext_vector_type(8)));
typedef float floatx4 __attribute__((ext_vector_type(4)));

#define NB 8
#define NS 1024
#define ND 512
#define NH 8
#define NDH 64
#define NBH 64
#define MROWS 8192
#define N3 1536

static __device__ __forceinline__ floatx4 mfma16(bf16x8 a, bf16x8 b, floatx4 c) {
    return __builtin_amdgcn_mfma_f32_16x16x32_bf16(a, b, c, 0, 0, 0);
}

// ---------------- zero ----------------
__global__ void zero_f32(float* p, int n) {
    int i = blockIdx.x * 256 + threadIdx.x;
    if (i < n) p[i] = 0.f;
}

// ---------------- W transpose+convert: Wb[e][d] = W[d][e] (e: Wq|Wk|Wv) ----------------
__global__ void convert_w(const float* __restrict__ Wq, const float* __restrict__ Wk,
                          const float* __restrict__ Wv, bf16* __restrict__ Wb) {
    __shared__ float t[32][33];
    int mat = blockIdx.z;
    const float* W = mat == 0 ? Wq : (mat == 1 ? Wk : Wv);
    int d0 = blockIdx.x * 32, e0 = blockIdx.y * 32;
    int tx = threadIdx.x, ty = threadIdx.y;  // 32, 8
#pragma unroll
    for (int i = 0; i < 4; i++) t[ty * 4 + i][tx] = W[(d0 + ty * 4 + i) * ND + e0 + tx];
    __syncthreads();
#pragma unroll
    for (int i = 0; i < 4; i++)
        Wb[(mat * ND + e0 + ty * 4 + i) * ND + d0 + tx] = (bf16)t[tx][ty * 4 + i];
}

// ---------------- GEMM1: QKV = relu(x @ W + b), bf16 out [8192][1536] ----------------
__launch_bounds__(256)
__global__ void gemm1(const float* __restrict__ x, const bf16* __restrict__ Wb,
                      const float* __restrict__ bq, const float* __restrict__ bk,
                      const float* __restrict__ bv, bf16* __restrict__ QKV) {
    __shared__ __align__(16) bf16 As[128][40];
    __shared__ __align__(16) bf16 Bs[128][40];
    int bm = blockIdx.x, bn = blockIdx.y;
    int t = threadIdx.x, lane = t & 63, w = t >> 6;
    int wr = w >> 1, wc = w & 1;
    int lr = lane & 15, lg = lane >> 4;
    int row0 = bm * 128, col0 = bn * 128;
    floatx4 acc[4][4] = {};
    for (int k0 = 0; k0 < ND; k0 += 32) {
        __syncthreads();
        {   // stage A (x fp32 -> bf16): 128 rows x 32 k
            int r = t >> 3, cg = t & 7;
#pragma unroll
            for (int rr = 0; rr < 128; rr += 32) {
                float4 v = *(const float4*)&x[(row0 + rr + r) * ND + k0 + cg * 4];
                bf16* dst = &As[rr + r][cg * 4];
                dst[0] = (bf16)v.x; dst[1] = (bf16)v.y; dst[2] = (bf16)v.z; dst[3] = (bf16)v.w;
            }
        }
        {   // stage B (Wb bf16): 128 e-rows x 32 k
            int r = t >> 2, cg = t & 3;
#pragma unroll
            for (int rr = 0; rr < 128; rr += 64)
                *(bf16x8*)&Bs[rr + r][cg * 8] =
                    *(const bf16x8*)&Wb[(col0 + rr + r) * ND + k0 + cg * 8];
        }
        __syncthreads();
        bf16x8 af[4], bfr[4];
#pragma unroll
        for (int mt = 0; mt < 4; mt++) af[mt] = *(const bf16x8*)&As[wr * 64 + mt * 16 + lr][lg * 8];
#pragma unroll
        for (int nt = 0; nt < 4; nt++) bfr[nt] = *(const bf16x8*)&Bs[wc * 64 + nt * 16 + lr][lg * 8];
#pragma unroll
        for (int mt = 0; mt < 4; mt++)
#pragma unroll
            for (int nt = 0; nt < 4; nt++)
                acc[mt][nt] = mfma16(af[mt], bfr[nt], acc[mt][nt]);
    }
#pragma unroll
    for (int mt = 0; mt < 4; mt++)
#pragma unroll
        for (int nt = 0; nt < 4; nt++) {
            int col = col0 + wc * 64 + nt * 16 + lr;
            float bias = col < 512 ? bq[col] : (col < 1024 ? bk[col - 512] : bv[col - 1024]);
#pragma unroll
            for (int r = 0; r < 4; r++) {
                int row = row0 + wr * 64 + mt * 16 + lg * 4 + r;
                float v = acc[mt][nt][r] + bias;
                v = v > 0.f ? v : 0.f;
                QKV[row * N3 + col] = (bf16)v;
            }
        }
}

// ---------------- V transpose: Vt[bh][d][s] = V[b][s][h][d] ----------------
__global__ void transpose_v(const bf16* __restrict__ QKV, bf16* __restrict__ Vt) {
    __shared__ __align__(16) bf16 tile[64][72];
    int bh = blockIdx.x, b = bh >> 3, h = bh & 7;
    int s0 = blockIdx.y * 64;
    int t = threadIdx.x;
    int sl = t >> 3, cg = t & 7;
#pragma unroll
    for (int rr = 0; rr < 64; rr += 32)
        *(bf16x8*)&tile[rr + sl][cg * 8] =
            *(const bf16x8*)&QKV[(b * NS + s0 + rr + sl) * N3 + 1024 + h * NDH + cg * 8];
    __syncthreads();
    int dl = t >> 3, sg = t & 7;
#pragma unroll
    for (int rr = 0; rr < 64; rr += 32) {
        bf16 tmp[8];
#pragma unroll
        for (int j = 0; j < 8; j++) tmp[j] = tile[sg * 8 + j][rr + dl];
        *(bf16x8*)&Vt[(bh * NDH + rr + dl) * NS + s0 + sg * 8] = *(bf16x8*)tmp;
    }
}

// ---------------- pass1: per-column (k) max & sum-exp over q ----------------
__launch_bounds__(256)
__global__ void attn_pass1(const bf16* __restrict__ QKV, float* __restrict__ m_arr,
                           float* __restrict__ rc_arr) {
    __shared__ __align__(16) bf16 Qs[128][72];
    __shared__ __align__(16) bf16 Ks[128][72];
    int bh = blockIdx.x, b = bh >> 3, h = bh & 7;
    int k0 = blockIdx.y * 128;
    int t = threadIdx.x, lane = t & 63, w = t >> 6;
    int lr = lane & 15, lg = lane >> 4;
    {   // stage K tile once: rows k0..k0+127
        int r = t >> 3, cg = t & 7;
#pragma unroll
        for (int rr = 0; rr < 128; rr += 32)
            *(bf16x8*)&Ks[rr + r][cg * 8] =
                *(const bf16x8*)&QKV[(b * NS + k0 + rr + r) * N3 + 512 + h * NDH + cg * 8];
    }
    float runM[2] = {-INFINITY, -INFINITY};
    float runC[2] = {0.f, 0.f};
    for (int q0 = 0; q0 < NS; q0 += 128) {
        __syncthreads();
        {   // stage Q tile
            int r = t >> 3, cg = t & 7;
#pragma unroll
            for (int rr = 0; rr < 128; rr += 32)
                *(bf16x8*)&Qs[rr + r][cg * 8] =
                    *(const bf16x8*)&QKV[(b * NS + q0 + rr + r) * N3 + h * NDH + cg * 8];
        }
        __syncthreads();
        floatx4 acc[8][2] = {};
#pragma unroll
        for (int ks = 0; ks < 2; ks++) {
            bf16x8 bfr[2];
#pragma unroll
            for (int nt = 0; nt < 2; nt++)
                bfr[nt] = *(const bf16x8*)&Ks[w * 32 + nt * 16 + lr][ks * 32 + lg * 8];
#pragma unroll
            for (int mt = 0; mt < 8; mt++) {
                bf16x8 af = *(const bf16x8*)&Qs[mt * 16 + lr][ks * 32 + lg * 8];
#pragma unroll
                for (int nt = 0; nt < 2; nt++) acc[mt][nt] = mfma16(af, bfr[nt], acc[mt][nt]);
            }
        }
#pragma unroll
        for (int nt = 0; nt < 2; nt++) {
            float tm = -INFINITY;
#pragma unroll
            for (int mt = 0; mt < 8; mt++)
#pragma unroll
                for (int r = 0; r < 4; r++) tm = fmaxf(tm, acc[mt][nt][r]);
            tm = fmaxf(tm, __shfl_xor(tm, 16));
            tm = fmaxf(tm, __shfl_xor(tm, 32));
            float tmS = tm * 0.125f;
            float ts = 0.f;
#pragma unroll
            for (int mt = 0; mt < 8; mt++)
#pragma unroll
                for (int r = 0; r < 4; r++) ts += __expf(acc[mt][nt][r] * 0.125f - tmS);
            ts += __shfl_xor(ts, 16);
            ts += __shfl_xor(ts, 32);
            float nm = fmaxf(runM[nt], tmS);
            runC[nt] = runC[nt] * __expf(runM[nt] - nm) + ts * __expf(tmS - nm);
            runM[nt] = nm;
        }
    }
    if (lane < 16) {
#pragma unroll
        for (int nt = 0; nt < 2; nt++) {
            int col = k0 + w * 32 + nt * 16 + lane;
            m_arr[bh * NS + col] = runM[nt];
            rc_arr[bh * NS + col] = 1.f / runC[nt];
        }
    }
}

// ---------------- pass2: out = E @ V' + x -> y (fp32, d_out) ----------------
__launch_bounds__(256)
__global__ void attn_pass2(const bf16* __restrict__ QKV, const bf16* __restrict__ Vt,
                           const float* __restrict__ m_arr, const float* __restrict__ rc_arr,
                           const float* __restrict__ x, float* __restrict__ y) {
    __shared__ __align__(16) bf16 Qs[128][72];
    __shared__ __align__(16) bf16 Ks[64][72];
    __shared__ __align__(16) bf16 Vs[64][72];
    __shared__ __align__(16) bf16 Es[128][72];
    int bh = blockIdx.x, b = bh >> 3, h = bh & 7;
    int q0 = blockIdx.y * 128;
    int t = threadIdx.x, lane = t & 63, w = t >> 6;
    int lr = lane & 15, lg = lane >> 4;
    int wr = w >> 1, wc = w & 1;
    {   // stage Q once
        int r = t >> 3, cg = t & 7;
#pragma unroll
        for (int rr = 0; rr < 128; rr += 32)
            *(bf16x8*)&Qs[rr + r][cg * 8] =
                *(const bf16x8*)&QKV[(b * NS + q0 + rr + r) * N3 + h * NDH + cg * 8];
    }
    floatx4 oacc[4][2] = {};
    for (int k0 = 0; k0 < NS; k0 += 64) {
        __syncthreads();  // prev-iter reads (and Q staging) done
        {   // stage K [64k][64d] and V^T [64d][64k]
            int r = t >> 2, cg = t & 3;
#pragma unroll
            for (int cc = 0; cc < 64; cc += 32)
                *(bf16x8*)&Ks[r][cc + cg * 8] =
                    *(const bf16x8*)&QKV[(b * NS + k0 + r) * N3 + 512 + h * NDH + cc + cg * 8];
#pragma unroll
            for (int cc = 0; cc < 64; cc += 32)
                *(bf16x8*)&Vs[r][cc + cg * 8] =
                    *(const bf16x8*)&Vt[(bh * NDH + r) * NS + k0 + cc + cg * 8];
        }
        __syncthreads();
        // scores: wave w -> q rows [w*32, w*32+32), all 64 k
        floatx4 sacc[2][4] = {};
#pragma unroll
        for (int ks = 0; ks < 2; ks++) {
            bf16x8 af[2];
#pragma unroll
            for (int mt = 0; mt < 2; mt++)
                af[mt] = *(const bf16x8*)&Qs[w * 32 + mt * 16 + lr][ks * 32 + lg * 8];
#pragma unroll
            for (int nt = 0; nt < 4; nt++) {
                bf16x8 bfr = *(const bf16x8*)&Ks[nt * 16 + lr][ks * 32 + lg * 8];
#pragma unroll
                for (int mt = 0; mt < 2; mt++) sacc[mt][nt] = mfma16(af[mt], bfr, sacc[mt][nt]);
            }
        }
#pragma unroll
        for (int nt = 0; nt < 4; nt++) {
            int col = k0 + nt * 16 + lr;
            float mm = m_arr[bh * NS + col];
            float rc = rc_arr[bh * NS + col];
#pragma unroll
            for (int mt = 0; mt < 2; mt++) {
                int qrow = w * 32 + mt * 16 + lg * 4;
#pragma unroll
                for (int r = 0; r < 4; r++) {
                    float e = __expf(sacc[mt][nt][r] * 0.125f - mm) * rc;
                    Es[qrow + r][nt * 16 + lr] = (bf16)e;
                }
            }
        }
        __syncthreads();
        // out += E @ V': wave (wr,wc): rows wr*64.., d cols wc*32..
#pragma unroll
        for (int ks = 0; ks < 2; ks++) {
            bf16x8 bfr[2];
#pragma unroll
            for (int nt = 0; nt < 2; nt++)
                bfr[nt] = *(const bf16x8*)&Vs[wc * 32 + nt * 16 + lr][ks * 32 + lg * 8];
#pragma unroll
            for (int mt = 0; mt < 4; mt++) {
                bf16x8 af = *(const bf16x8*)&Es[wr * 64 + mt * 16 + lr][ks * 32 + lg * 8];
#pragma unroll
                for (int nt = 0; nt < 2; nt++) oacc[mt][nt] = mfma16(af, bfr[nt], oacc[mt][nt]);
            }
        }
    }
#pragma unroll
    for (int mt = 0; mt < 4; mt++)
#pragma unroll
        for (int nt = 0; nt < 2; nt++) {
            int dcol = wc * 32 + nt * 16 + lr;
#pragma unroll
            for (int r = 0; r < 4; r++) {
                int q = q0 + wr * 64 + mt * 16 + lg * 4 + r;
                int idx = (b * NS + q) * ND + h * NDH + dcol;
                y[idx] = oacc[mt][nt][r] + x[idx];
            }
        }
}

// ---------------- BN stats ----------------
__global__ void bn_stats(const float* __restrict__ y, float* __restrict__ bnSum,
                         float* __restrict__ bnSumSq) {
    int blk = blockIdx.x;  // 256 blocks x 32 rows
    int t = threadIdx.x;
    int c = t, c2 = t + 256;
    float s1 = 0, q1 = 0, s2 = 0, q2 = 0;
    int r0 = blk * 32;
    for (int r = 0; r < 32; r++) {
        float a = y[(r0 + r) * ND + c];
        s1 += a; q1 += a * a;
        float bb = y[(r0 + r) * ND + c2];
        s2 += bb; q2 += bb * bb;
    }
    atomicAdd(&bnSum[c], s1);
    atomicAdd(&bnSumSq[c], q1);
    atomicAdd(&bnSum[c2], s2);
    atomicAdd(&bnSumSq[c2], q2);
}

// ---------------- BN apply (in place on y) ----------------
__global__ void bn_apply(float* __restrict__ y, const float* __restrict__ bnSum,
                         const float* __restrict__ bnSumSq, const float* __restrict__ gamma,
                         const float* __restrict__ beta) {
    int i = (blockIdx.x * 256 + threadIdx.x) * 4;
    int c = i & 511;
    float4 v = *(float4*)&y[i];
    float vv[4] = {v.x, v.y, v.z, v.w};
    float out[4];
#pragma unroll
    for (int j = 0; j < 4; j++) {
        float mean = bnSum[c + j] * (1.f / 8192.f);
        float var = bnSumSq[c + j] * (1.f / 8192.f) - mean * mean;
        float rstd = rsqrtf(var + 1e-5f);
        out[j] = (vv[j] - mean) * rstd * gamma[c + j] + beta[c + j];
    }
    *(float4*)&y[i] = make_float4(out[0], out[1], out[2], out[3]);
}

extern "C" void kernel_launch(void* const* d_in, const int* in_sizes, int n_in,
                              void* d_out, int out_size, void* d_ws, size_t ws_size,
                              hipStream_t stream) {
    const float* x  = (const float*)d_in[0];
    const float* Wq = (const float*)d_in[1];
    const float* bq = (const float*)d_in[2];
    const float* Wk = (const float*)d_in[3];
    const float* bk = (const float*)d_in[4];
    const float* Wv = (const float*)d_in[5];
    const float* bv = (const float*)d_in[6];
    const float* gamma = (const float*)d_in[7];
    const float* beta  = (const float*)d_in[8];
    float* y = (float*)d_out;

    char* ws = (char*)d_ws;
    const size_t WB_OFF  = 0;
    const size_t QKV_OFF = 2u << 20;                          // 2 MiB
    const size_t VT_OFF  = QKV_OFF + (size_t)MROWS * N3 * 2;  // +24 MiB
    const size_t M_OFF   = VT_OFF + (size_t)NBH * NDH * NS * 2;
    const size_t RC_OFF  = M_OFF + (size_t)NBH * NS * 4;
    const size_t BN_OFF  = RC_OFF + (size_t)NBH * NS * 4;
    bf16*  Wb     = (bf16*)(ws + WB_OFF);
    bf16*  QKV    = (bf16*)(ws + QKV_OFF);
    bf16*  Vt     = (bf16*)(ws + VT_OFF);
    float* m_arr  = (float*)(ws + M_OFF);
    float* rc_arr = (float*)(ws + RC_OFF);
    float* bnSum  = (float*)(ws + BN_OFF);
    float* bnSumSq = bnSum + 512;

    zero_f32<<<4, 256, 0, stream>>>(bnSum, 1024);
    convert_w<<<dim3(16, 16, 3), dim3(32, 8), 0, stream>>>(Wq, Wk, Wv, Wb);
    gemm1<<<dim3(64, 12), 256, 0, stream>>>(x, Wb, bq, bk, bv, QKV);
    transpose_v<<<dim3(64, 16), 256, 0, stream>>>(QKV, Vt);
    attn_pass1<<<dim3(64, 8), 256, 0, stream>>>(QKV, m_arr, rc_arr);
    attn_pass2<<<dim3(64, 8), 256, 0, stream>>>(QKV, Vt, m_arr, rc_arr, x, y);
    bn_stats<<<256, 256, 0, stream>>>(y, bnSum, bnSumSq);
    bn_apply<<<4096, 256, 0, stream>>>(y, bnSum, bnSumSq, gamma, beta);
}

// Round 2
// 114.310 us; speedup vs baseline: 1.0998x; 1.0998x over previous
//
#include <hip/hip_runtime.h>
#include <hip/hip_bf16.h>
#include <math.h>

typedef __bf16 bf16;
typedef __bf16 bf16x8 __attribute__((ext_vector_type(8)));
typedef float floatx4 __attribute__((ext_vector_type(4)));

#define NB 8
#define NS 1024
#define ND 512
#define NH 8
#define NDH 64
#define NBH 64
#define MROWS 8192
#define N3 1536

static __device__ __forceinline__ floatx4 mfma16(bf16x8 a, bf16x8 b, floatx4 c) {
    return __builtin_amdgcn_mfma_f32_16x16x32_bf16(a, b, c, 0, 0, 0);
}

static __device__ __forceinline__ unsigned pack2(float lo, float hi) {
    union { bf16 h[2]; unsigned u; } u;
    u.h[0] = (bf16)lo; u.h[1] = (bf16)hi;
    return u.u;
}

static __device__ __forceinline__ void plane32(unsigned &a, unsigned &b) {
    asm volatile("v_permlane32_swap_b32 %0, %1" : "+v"(a), "+v"(b));
}
static __device__ __forceinline__ void plane16(unsigned &a, unsigned &b) {
    asm volatile("v_permlane16_swap_b32 %0, %1" : "+v"(a), "+v"(b));
}

// ---------------- zero ----------------
__global__ void zero_f32(float* p, int n) {
    int i = blockIdx.x * 256 + threadIdx.x;
    if (i < n) p[i] = 0.f;
}

// ---------------- W transpose+convert: Wb[e][d] = W[d][e] (e: Wq|Wk|Wv) ----------------
__global__ void convert_w(const float* __restrict__ Wq, const float* __restrict__ Wk,
                          const float* __restrict__ Wv, bf16* __restrict__ Wb) {
    __shared__ float t[32][33];
    int mat = blockIdx.z;
    const float* W = mat == 0 ? Wq : (mat == 1 ? Wk : Wv);
    int d0 = blockIdx.x * 32, e0 = blockIdx.y * 32;
    int tx = threadIdx.x, ty = threadIdx.y;  // 32, 8
#pragma unroll
    for (int i = 0; i < 4; i++) t[ty * 4 + i][tx] = W[(d0 + ty * 4 + i) * ND + e0 + tx];
    __syncthreads();
#pragma unroll
    for (int i = 0; i < 4; i++)
        Wb[(mat * ND + e0 + ty * 4 + i) * ND + d0 + tx] = (bf16)t[tx][ty * 4 + i];
}

// ---------------- GEMM1: QKV = relu(x @ W + b), bf16 out [8192][1536] ----------------
__launch_bounds__(256)
__global__ void gemm1(const float* __restrict__ x, const bf16* __restrict__ Wb,
                      const float* __restrict__ bq, const float* __restrict__ bk,
                      const float* __restrict__ bv, bf16* __restrict__ QKV) {
    __shared__ __align__(16) bf16 As[128][40];
    __shared__ __align__(16) bf16 Bs[128][40];
    int bm = blockIdx.x, bn = blockIdx.y;
    int t = threadIdx.x, lane = t & 63, w = t >> 6;
    int wr = w >> 1, wc = w & 1;
    int lr = lane & 15, lg = lane >> 4;
    int row0 = bm * 128, col0 = bn * 128;
    floatx4 acc[4][4] = {};
    for (int k0 = 0; k0 < ND; k0 += 32) {
        __syncthreads();
        {   // stage A (x fp32 -> bf16): 128 rows x 32 k
            int r = t >> 3, cg = t & 7;
#pragma unroll
            for (int rr = 0; rr < 128; rr += 32) {
                float4 v = *(const float4*)&x[(row0 + rr + r) * ND + k0 + cg * 4];
                bf16* dst = &As[rr + r][cg * 4];
                dst[0] = (bf16)v.x; dst[1] = (bf16)v.y; dst[2] = (bf16)v.z; dst[3] = (bf16)v.w;
            }
        }
        {   // stage B (Wb bf16): 128 e-rows x 32 k
            int r = t >> 2, cg = t & 3;
#pragma unroll
            for (int rr = 0; rr < 128; rr += 64)
                *(bf16x8*)&Bs[rr + r][cg * 8] =
                    *(const bf16x8*)&Wb[(col0 + rr + r) * ND + k0 + cg * 8];
        }
        __syncthreads();
        bf16x8 af[4], bfr[4];
#pragma unroll
        for (int mt = 0; mt < 4; mt++) af[mt] = *(const bf16x8*)&As[wr * 64 + mt * 16 + lr][lg * 8];
#pragma unroll
        for (int nt = 0; nt < 4; nt++) bfr[nt] = *(const bf16x8*)&Bs[wc * 64 + nt * 16 + lr][lg * 8];
#pragma unroll
        for (int mt = 0; mt < 4; mt++)
#pragma unroll
            for (int nt = 0; nt < 4; nt++)
                acc[mt][nt] = mfma16(af[mt], bfr[nt], acc[mt][nt]);
    }
#pragma unroll
    for (int mt = 0; mt < 4; mt++)
#pragma unroll
        for (int nt = 0; nt < 4; nt++) {
            int col = col0 + wc * 64 + nt * 16 + lr;
            float bias = col < 512 ? bq[col] : (col < 1024 ? bk[col - 512] : bv[col - 1024]);
#pragma unroll
            for (int r = 0; r < 4; r++) {
                int row = row0 + wr * 64 + mt * 16 + lg * 4 + r;
                float v = acc[mt][nt][r] + bias;
                v = v > 0.f ? v : 0.f;
                QKV[row * N3 + col] = (bf16)v;
            }
        }
}

// ---------------- V transpose: Vt[bh][d][s] = V[b][s][h][d] ----------------
__global__ void transpose_v(const bf16* __restrict__ QKV, bf16* __restrict__ Vt) {
    __shared__ __align__(16) bf16 tile[64][72];
    int bh = blockIdx.x, b = bh >> 3, h = bh & 7;
    int s0 = blockIdx.y * 64;
    int t = threadIdx.x;
    int sl = t >> 3, cg = t & 7;
#pragma unroll
    for (int rr = 0; rr < 64; rr += 32)
        *(bf16x8*)&tile[rr + sl][cg * 8] =
            *(const bf16x8*)&QKV[(b * NS + s0 + rr + sl) * N3 + 1024 + h * NDH + cg * 8];
    __syncthreads();
    int dl = t >> 3, sg = t & 7;
#pragma unroll
    for (int rr = 0; rr < 64; rr += 32) {
        bf16 tmp[8];
#pragma unroll
        for (int j = 0; j < 8; j++) tmp[j] = tile[sg * 8 + j][rr + dl];
        *(bf16x8*)&Vt[(bh * NDH + rr + dl) * NS + s0 + sg * 8] = *(bf16x8*)tmp;
    }
}

// ---------------- pass1: rc[k] = 1 / sum_q exp(s[q,k]/8)  (no max needed: s>=0, bounded) ----
__launch_bounds__(256)
__global__ void attn_colsum(const bf16* __restrict__ QKV, float* __restrict__ rc_arr) {
    __shared__ __align__(16) bf16 Qs[128][72];
    int bh = blockIdx.x, b = bh >> 3, h = bh & 7;
    int k0 = blockIdx.y * 128;
    int t = threadIdx.x, lane = t & 63, w = t >> 6;
    int lr = lane & 15, lg = lane >> 4;
    // K fragments (A operand of swapped mfma) held in registers for whole kernel
    bf16x8 kf[2][2];
#pragma unroll
    for (int tt = 0; tt < 2; tt++)
#pragma unroll
        for (int s = 0; s < 2; s++)
            kf[tt][s] = *(const bf16x8*)&QKV[(size_t)(b * NS + k0 + w * 32 + tt * 16 + lr) * N3 +
                                             512 + h * NDH + s * 32 + lg * 8];
    floatx4 csum[2] = {};
    const floatx4 zf = {};
    for (int qc = 0; qc < 8; qc++) {
        __syncthreads();
        {   // stage Q chunk [128][64]
            int r0 = t >> 3, c0 = (t & 7) * 8;
#pragma unroll
            for (int rr = 0; rr < 128; rr += 32)
                *(bf16x8*)&Qs[r0 + rr][c0] =
                    *(const bf16x8*)&QKV[(size_t)(b * NS + qc * 128 + r0 + rr) * N3 + h * NDH + c0];
        }
        __syncthreads();
#pragma unroll
        for (int qt = 0; qt < 8; qt++) {
            bf16x8 qb0 = *(const bf16x8*)&Qs[qt * 16 + lr][lg * 8];
            bf16x8 qb1 = *(const bf16x8*)&Qs[qt * 16 + lr][32 + lg * 8];
#pragma unroll
            for (int tt = 0; tt < 2; tt++) {
                floatx4 a = mfma16(kf[tt][0], qb0, zf);
                a = mfma16(kf[tt][1], qb1, a);
#pragma unroll
                for (int r = 0; r < 4; r++) csum[tt][r] += __expf(a[r] * 0.125f);
            }
        }
    }
    // sum across the 16 lanes (q-residues) within each lane-group
#pragma unroll
    for (int tt = 0; tt < 2; tt++)
#pragma unroll
        for (int r = 0; r < 4; r++) {
            float v = csum[tt][r];
            v += __shfl_xor(v, 1);
            v += __shfl_xor(v, 2);
            v += __shfl_xor(v, 4);
            v += __shfl_xor(v, 8);
            csum[tt][r] = v;
        }
    if (lr == 0) {
#pragma unroll
        for (int tt = 0; tt < 2; tt++)
#pragma unroll
            for (int r = 0; r < 4; r++)
                rc_arr[bh * NS + k0 + w * 32 + tt * 16 + lg * 4 + r] = 1.f / csum[tt][r];
    }
}

// ---------------- pass2: y = E @ V + x, E kept in-register via permlane transpose ----------
__launch_bounds__(256)
__global__ void attn_fused(const bf16* __restrict__ QKV, const bf16* __restrict__ Vt,
                           const float* __restrict__ rc_arr, const float* __restrict__ x,
                           float* __restrict__ y) {
    __shared__ __align__(16) bf16 Ks[128][72];
    __shared__ __align__(16) bf16 Vs[64][136];
    int bh = blockIdx.x, b = bh >> 3, h = bh & 7;
    int q0 = blockIdx.y * 128;
    int t = threadIdx.x, lane = t & 63, w = t >> 6;
    int lr = lane & 15, lg = lane >> 4;
    // Q fragments (B operand of swapped score mfma) in registers for whole kernel
    bf16x8 qf[2][2];
#pragma unroll
    for (int n = 0; n < 2; n++)
#pragma unroll
        for (int s = 0; s < 2; s++)
            qf[n][s] = *(const bf16x8*)&QKV[(size_t)(b * NS + q0 + w * 32 + n * 16 + lr) * N3 +
                                            h * NDH + s * 32 + lg * 8];
    floatx4 oacc[2][4] = {};
    const floatx4 zf = {};
    for (int k0 = 0; k0 < NS; k0 += 128) {
        __syncthreads();
        {   // stage K [128 k][64 dh]
            int r0 = t >> 3, c0 = (t & 7) * 8;
#pragma unroll
            for (int rr = 0; rr < 128; rr += 32)
                *(bf16x8*)&Ks[r0 + rr][c0] =
                    *(const bf16x8*)&QKV[(size_t)(b * NS + k0 + r0 + rr) * N3 + 512 + h * NDH + c0];
        }
        {   // stage V^T [64 d][128 k]
            int d0 = t >> 4, c1 = (t & 15) * 8;
#pragma unroll
            for (int dd = 0; dd < 64; dd += 16)
                *(bf16x8*)&Vs[d0 + dd][c1] =
                    *(const bf16x8*)&Vt[(size_t)(bh * NDH + d0 + dd) * NS + k0 + c1];
        }
        __syncthreads();
#pragma unroll
        for (int kt = 0; kt < 4; kt++) {
            // K A-fragments for this 32-k slice
            bf16x8 kfr[2][2];
#pragma unroll
            for (int tt = 0; tt < 2; tt++)
#pragma unroll
                for (int s = 0; s < 2; s++)
                    kfr[tt][s] = *(const bf16x8*)&Ks[kt * 32 + tt * 16 + lr][s * 32 + lg * 8];
            // per-column normalizers (same for both q subtiles)
            float4 rcv0 = *(const float4*)&rc_arr[bh * NS + k0 + kt * 32 + lg * 4];
            float4 rcv1 = *(const float4*)&rc_arr[bh * NS + k0 + kt * 32 + 16 + lg * 4];
            const float* rc0 = &rcv0.x;
            const float* rc1 = &rcv1.x;
            // V B-fragments
            bf16x8 vf[4];
#pragma unroll
            for (int nt = 0; nt < 4; nt++)
                vf[nt] = *(const bf16x8*)&Vs[nt * 16 + lr][kt * 32 + lg * 8];
#pragma unroll
            for (int n = 0; n < 2; n++) {
                // swapped scores: C[m=k'][n=q]
                floatx4 s0 = mfma16(kfr[0][0], qf[n][0], zf);
                s0 = mfma16(kfr[0][1], qf[n][1], s0);
                floatx4 s1 = mfma16(kfr[1][0], qf[n][0], zf);
                s1 = mfma16(kfr[1][1], qf[n][1], s1);
                // E = exp(s/8) * rc[k']
                float e0[4], e1[4];
#pragma unroll
                for (int r = 0; r < 4; r++) {
                    e0[r] = __expf(s0[r] * 0.125f) * rc0[r];
                    e1[r] = __expf(s1[r] * 0.125f) * rc1[r];
                }
                // in-register transpose to PV A-fragment layout
                unsigned A0 = pack2(e0[0], e0[1]);
                unsigned A1 = pack2(e0[2], e0[3]);
                unsigned B0 = pack2(e1[0], e1[1]);
                unsigned B1 = pack2(e1[2], e1[3]);
                plane32(A0, B0); plane16(A0, B0);  // A0=dw0, B0=dw2
                plane32(A1, B1); plane16(A1, B1);  // A1=dw1, B1=dw3
                union { unsigned u[4]; bf16x8 v; } af;
                af.u[0] = A0; af.u[1] = A1; af.u[2] = B0; af.u[3] = B1;
#pragma unroll
                for (int nt = 0; nt < 4; nt++)
                    oacc[n][nt] = mfma16(af.v, vf[nt], oacc[n][nt]);
            }
        }
    }
    // epilogue: out[q][d] + residual
#pragma unroll
    for (int n = 0; n < 2; n++)
#pragma unroll
        for (int nt = 0; nt < 4; nt++) {
            int d = nt * 16 + lr;
#pragma unroll
            for (int r = 0; r < 4; r++) {
                int q = q0 + w * 32 + n * 16 + lg * 4 + r;
                size_t idx = (size_t)(b * NS + q) * ND + h * NDH + d;
                y[idx] = oacc[n][nt][r] + x[idx];
            }
        }
}

// ---------------- BN stats ----------------
__global__ void bn_stats(const float* __restrict__ y, float* __restrict__ bnSum,
                         float* __restrict__ bnSumSq) {
    int blk = blockIdx.x;  // 256 blocks x 32 rows
    int t = threadIdx.x;
    int c = t, c2 = t + 256;
    float s1 = 0, q1 = 0, s2 = 0, q2 = 0;
    int r0 = blk * 32;
    for (int r = 0; r < 32; r++) {
        float a = y[(r0 + r) * ND + c];
        s1 += a; q1 += a * a;
        float bb = y[(r0 + r) * ND + c2];
        s2 += bb; q2 += bb * bb;
    }
    atomicAdd(&bnSum[c], s1);
    atomicAdd(&bnSumSq[c], q1);
    atomicAdd(&bnSum[c2], s2);
    atomicAdd(&bnSumSq[c2], q2);
}

// ---------------- BN apply (in place on y) ----------------
__global__ void bn_apply(float* __restrict__ y, const float* __restrict__ bnSum,
                         const float* __restrict__ bnSumSq, const float* __restrict__ gamma,
                         const float* __restrict__ beta) {
    int i = (blockIdx.x * 256 + threadIdx.x) * 4;
    int c = i & 511;
    float4 v = *(float4*)&y[i];
    float vv[4] = {v.x, v.y, v.z, v.w};
    float out[4];
#pragma unroll
    for (int j = 0; j < 4; j++) {
        float mean = bnSum[c + j] * (1.f / 8192.f);
        float var = bnSumSq[c + j] * (1.f / 8192.f) - mean * mean;
        float rstd = rsqrtf(var + 1e-5f);
        out[j] = (vv[j] - mean) * rstd * gamma[c + j] + beta[c + j];
    }
    *(float4*)&y[i] = make_float4(out[0], out[1], out[2], out[3]);
}

extern "C" void kernel_launch(void* const* d_in, const int* in_sizes, int n_in,
                              void* d_out, int out_size, void* d_ws, size_t ws_size,
                              hipStream_t stream) {
    const float* x  = (const float*)d_in[0];
    const float* Wq = (const float*)d_in[1];
    const float* bq = (const float*)d_in[2];
    const float* Wk = (const float*)d_in[3];
    const float* bk = (const float*)d_in[4];
    const float* Wv = (const float*)d_in[5];
    const float* bv = (const float*)d_in[6];
    const float* gamma = (const float*)d_in[7];
    const float* beta  = (const float*)d_in[8];
    float* y = (float*)d_out;

    char* ws = (char*)d_ws;
    const size_t WB_OFF  = 0;
    const size_t QKV_OFF = 2u << 20;                          // 2 MiB
    const size_t VT_OFF  = QKV_OFF + (size_t)MROWS * N3 * 2;  // +24 MiB
    const size_t RC_OFF  = VT_OFF + (size_t)NBH * NDH * NS * 2;
    const size_t BN_OFF  = RC_OFF + (size_t)NBH * NS * 4;
    bf16*  Wb     = (bf16*)(ws + WB_OFF);
    bf16*  QKV    = (bf16*)(ws + QKV_OFF);
    bf16*  Vt     = (bf16*)(ws + VT_OFF);
    float* rc_arr = (float*)(ws + RC_OFF);
    float* bnSum  = (float*)(ws + BN_OFF);
    float* bnSumSq = bnSum + 512;

    zero_f32<<<4, 256, 0, stream>>>(bnSum, 1024);
    convert_w<<<dim3(16, 16, 3), dim3(32, 8), 0, stream>>>(Wq, Wk, Wv, Wb);
    gemm1<<<dim3(64, 12), 256, 0, stream>>>(x, Wb, bq, bk, bv, QKV);
    transpose_v<<<dim3(64, 16), 256, 0, stream>>>(QKV, Vt);
    attn_colsum<<<dim3(64, 8), 256, 0, stream>>>(QKV, rc_arr);
    attn_fused<<<dim3(64, 8), 256, 0, stream>>>(QKV, Vt, rc_arr, x, y);
    bn_stats<<<256, 256, 0, stream>>>(y, bnSum, bnSumSq);
    bn_apply<<<4096, 256, 0, stream>>>(y, bnSum, bnSumSq, gamma, beta);
}

// Round 3
// 98.443 us; speedup vs baseline: 1.2771x; 1.1612x over previous
//
#include <hip/hip_runtime.h>
#include <hip/hip_bf16.h>
#include <math.h>

typedef __bf16 bf16;
typedef __bf16 bf16x8 __attribute__((ext_vector_type(8)));
typedef float floatx4 __attribute__((ext_vector_type(4)));

#define NB 8
#define NS 1024
#define ND 512
#define NH 8
#define NDH 64
#define NBH 64
#define MROWS 8192
#define N3 1536

#define GLD16(src, dst)                                                            \
    __builtin_amdgcn_global_load_lds(                                              \
        (const __attribute__((address_space(1))) void*)(src),                      \
        (__attribute__((address_space(3))) void*)(dst), 16, 0, 0)

static __device__ __forceinline__ floatx4 mfma16(bf16x8 a, bf16x8 b, floatx4 c) {
    return __builtin_amdgcn_mfma_f32_16x16x32_bf16(a, b, c, 0, 0, 0);
}

static __device__ __forceinline__ unsigned pack2(float lo, float hi) {
    union { bf16 h[2]; unsigned u; } u;
    u.h[0] = (bf16)lo; u.h[1] = (bf16)hi;
    return u.u;
}

static __device__ __forceinline__ void plane32(unsigned &a, unsigned &b) {
    asm volatile("v_permlane32_swap_b32 %0, %1" : "+v"(a), "+v"(b));
}
static __device__ __forceinline__ void plane16(unsigned &a, unsigned &b) {
    asm volatile("v_permlane16_swap_b32 %0, %1" : "+v"(a), "+v"(b));
}

// ---------------- zero ----------------
__global__ void zero_f32(float* p, int n) {
    int i = blockIdx.x * 256 + threadIdx.x;
    if (i < n) p[i] = 0.f;
}

// ---------------- x fp32 -> bf16 ----------------
__global__ void convert_x(const float* __restrict__ x, bf16* __restrict__ xb) {
    int i = (blockIdx.x * 256 + threadIdx.x) * 8;
    float4 a = *(const float4*)&x[i];
    float4 b = *(const float4*)&x[i + 4];
    bf16 o[8] = {(bf16)a.x, (bf16)a.y, (bf16)a.z, (bf16)a.w,
                 (bf16)b.x, (bf16)b.y, (bf16)b.z, (bf16)b.w};
    *(bf16x8*)&xb[i] = *(bf16x8*)o;
}

// ---------------- W transpose+convert: Wb[e][d] = W[d][e] (e: Wq|Wk|Wv) ----------------
__global__ void convert_w(const float* __restrict__ Wq, const float* __restrict__ Wk,
                          const float* __restrict__ Wv, bf16* __restrict__ Wb) {
    __shared__ float t[32][33];
    int mat = blockIdx.z;
    const float* W = mat == 0 ? Wq : (mat == 1 ? Wk : Wv);
    int d0 = blockIdx.x * 32, e0 = blockIdx.y * 32;
    int tx = threadIdx.x, ty = threadIdx.y;  // 32, 8
#pragma unroll
    for (int i = 0; i < 4; i++) t[ty * 4 + i][tx] = W[(d0 + ty * 4 + i) * ND + e0 + tx];
    __syncthreads();
#pragma unroll
    for (int i = 0; i < 4; i++)
        Wb[(mat * ND + e0 + ty * 4 + i) * ND + d0 + tx] = (bf16)t[tx][ty * 4 + i];
}

// ---------------- GEMM1: QKV = relu(xb @ Wb^T + b), m97-style, swizzled LDS ----------------
__launch_bounds__(256)
__global__ void gemm1(const bf16* __restrict__ xb, const bf16* __restrict__ Wb,
                      const float* __restrict__ bq, const float* __restrict__ bk,
                      const float* __restrict__ bv, bf16* __restrict__ QKV) {
    __shared__ __align__(16) bf16 As[128 * 64];
    __shared__ __align__(16) bf16 Bs[128 * 64];
    int t = threadIdx.x, lane = t & 63, w = t >> 6;
    int wr = w >> 1, wc = w & 1;
    int lr = lane & 15, lg = lane >> 4;
    int row0 = blockIdx.x * 128, col0 = blockIdx.y * 128;
    int srow = t >> 3, sj = t & 7;  // staging: chunk row/slot at it=0
    floatx4 acc[4][4] = {};
    for (int k0 = 0; k0 < ND; k0 += 64) {
        __syncthreads();
#pragma unroll
        for (int it = 0; it < 4; it++) {
            int row = it * 32 + srow;
            int j = sj ^ (row & 7);
            GLD16(&xb[(size_t)(row0 + row) * ND + k0 + j * 8], &As[(it * 256 + w * 64) * 8]);
            GLD16(&Wb[(size_t)(col0 + row) * ND + k0 + j * 8], &Bs[(it * 256 + w * 64) * 8]);
        }
        __syncthreads();
        bf16x8 af[2][4], bfr[2][4];
#pragma unroll
        for (int ks = 0; ks < 2; ks++) {
#pragma unroll
            for (int mt = 0; mt < 4; mt++)
                af[ks][mt] = *(const bf16x8*)&As[(wr * 64 + mt * 16 + lr) * 64 +
                                                 ((ks * 4 + lg) ^ (lr & 7)) * 8];
#pragma unroll
            for (int nt = 0; nt < 4; nt++)
                bfr[ks][nt] = *(const bf16x8*)&Bs[(wc * 64 + nt * 16 + lr) * 64 +
                                                  ((ks * 4 + lg) ^ (lr & 7)) * 8];
        }
#pragma unroll
        for (int ks = 0; ks < 2; ks++)
#pragma unroll
            for (int mt = 0; mt < 4; mt++)
#pragma unroll
                for (int nt = 0; nt < 4; nt++)
                    acc[mt][nt] = mfma16(af[ks][mt], bfr[ks][nt], acc[mt][nt]);
    }
#pragma unroll
    for (int mt = 0; mt < 4; mt++)
#pragma unroll
        for (int nt = 0; nt < 4; nt++) {
            int col = col0 + wc * 64 + nt * 16 + lr;
            float bias = col < 512 ? bq[col] : (col < 1024 ? bk[col - 512] : bv[col - 1024]);
#pragma unroll
            for (int r = 0; r < 4; r++) {
                int row = row0 + wr * 64 + mt * 16 + lg * 4 + r;
                float v = acc[mt][nt][r] + bias;
                v = v > 0.f ? v : 0.f;
                QKV[(size_t)row * N3 + col] = (bf16)v;
            }
        }
}

// ---------------- pass1: rc[k] = 1 / sum_q exp(s[q,k]/8)  (s>=0, no max needed) ----------
__launch_bounds__(256)
__global__ void attn_colsum(const bf16* __restrict__ QKV, float* __restrict__ rc_arr) {
    __shared__ __align__(16) bf16 Qs[128 * 64];
    int bh = blockIdx.x, b = bh >> 3, h = bh & 7;
    int k0 = blockIdx.y * 128;
    int t = threadIdx.x, lane = t & 63, w = t >> 6;
    int lr = lane & 15, lg = lane >> 4;
    int srow = t >> 3, sj = t & 7;
    // K fragments (A operand of swapped mfma) held in registers for whole kernel
    bf16x8 kf[2][2];
#pragma unroll
    for (int tt = 0; tt < 2; tt++)
#pragma unroll
        for (int s = 0; s < 2; s++)
            kf[tt][s] = *(const bf16x8*)&QKV[(size_t)(b * NS + k0 + w * 32 + tt * 16 + lr) * N3 +
                                             512 + h * NDH + s * 32 + lg * 8];
    floatx4 csum[2] = {};
    const floatx4 zf = {};
    for (int qc = 0; qc < 8; qc++) {
        __syncthreads();
#pragma unroll
        for (int it = 0; it < 4; it++) {
            int row = it * 32 + srow;
            int j = sj ^ (row & 7);
            GLD16(&QKV[(size_t)(b * NS + qc * 128 + row) * N3 + h * NDH + j * 8],
                  &Qs[(it * 256 + w * 64) * 8]);
        }
        __syncthreads();
#pragma unroll
        for (int qt = 0; qt < 8; qt++) {
            bf16x8 qb0 = *(const bf16x8*)&Qs[(qt * 16 + lr) * 64 + (lg ^ (lr & 7)) * 8];
            bf16x8 qb1 = *(const bf16x8*)&Qs[(qt * 16 + lr) * 64 + ((4 + lg) ^ (lr & 7)) * 8];
#pragma unroll
            for (int tt = 0; tt < 2; tt++) {
                floatx4 a = mfma16(kf[tt][0], qb0, zf);
                a = mfma16(kf[tt][1], qb1, a);
#pragma unroll
                for (int r = 0; r < 4; r++) csum[tt][r] += __expf(a[r] * 0.125f);
            }
        }
    }
#pragma unroll
    for (int tt = 0; tt < 2; tt++)
#pragma unroll
        for (int r = 0; r < 4; r++) {
            float v = csum[tt][r];
            v += __shfl_xor(v, 1);
            v += __shfl_xor(v, 2);
            v += __shfl_xor(v, 4);
            v += __shfl_xor(v, 8);
            csum[tt][r] = v;
        }
    if (lr == 0) {
#pragma unroll
        for (int tt = 0; tt < 2; tt++)
#pragma unroll
            for (int r = 0; r < 4; r++)
                rc_arr[bh * NS + k0 + w * 32 + tt * 16 + lg * 4 + r] = 1.f / csum[tt][r];
    }
}

// ---------------- V transpose + rc scale: Vt[bh][d][s] = V[b][s][h][d] * rc[bh][s] --------
__global__ void transpose_v(const bf16* __restrict__ QKV, const float* __restrict__ rc_arr,
                            bf16* __restrict__ Vt) {
    __shared__ __align__(16) bf16 tile[64][72];
    int bh = blockIdx.x, b = bh >> 3, h = bh & 7;
    int s0 = blockIdx.y * 64;
    int t = threadIdx.x;
    int sl = t >> 3, cg = t & 7;
#pragma unroll
    for (int rr = 0; rr < 64; rr += 32)
        *(bf16x8*)&tile[rr + sl][cg * 8] =
            *(const bf16x8*)&QKV[(size_t)(b * NS + s0 + rr + sl) * N3 + 1024 + h * NDH + cg * 8];
    __syncthreads();
    int dl = t >> 3, sg = t & 7;
    float4 rc0 = *(const float4*)&rc_arr[bh * NS + s0 + sg * 8];
    float4 rc1 = *(const float4*)&rc_arr[bh * NS + s0 + sg * 8 + 4];
    float rcv[8] = {rc0.x, rc0.y, rc0.z, rc0.w, rc1.x, rc1.y, rc1.z, rc1.w};
#pragma unroll
    for (int rr = 0; rr < 64; rr += 32) {
        bf16 tmp[8];
#pragma unroll
        for (int j = 0; j < 8; j++)
            tmp[j] = (bf16)((float)tile[sg * 8 + j][rr + dl] * rcv[j]);
        *(bf16x8*)&Vt[(size_t)(bh * NDH + rr + dl) * NS + s0 + sg * 8] = *(bf16x8*)tmp;
    }
}

// ---------------- pass2: y = E @ V' + x; BN partial sums fused ----------------
__launch_bounds__(256)
__global__ void attn_fused(const bf16* __restrict__ QKV, const bf16* __restrict__ Vt,
                           const float* __restrict__ x, float* __restrict__ y,
                           float* __restrict__ bnSum, float* __restrict__ bnSumSq) {
    __shared__ __align__(16) bf16 Ks[128 * 64];
    __shared__ __align__(16) bf16 Vs[64 * 128];
    int bh = blockIdx.x, b = bh >> 3, h = bh & 7;
    int q0 = blockIdx.y * 128;
    int t = threadIdx.x, lane = t & 63, w = t >> 6;
    int lr = lane & 15, lg = lane >> 4;
    // Q fragments (B operand of swapped score mfma) in registers for whole kernel
    bf16x8 qf[2][2];
#pragma unroll
    for (int n = 0; n < 2; n++)
#pragma unroll
        for (int s = 0; s < 2; s++)
            qf[n][s] = *(const bf16x8*)&QKV[(size_t)(b * NS + q0 + w * 32 + n * 16 + lr) * N3 +
                                            h * NDH + s * 32 + lg * 8];
    floatx4 oacc[2][4] = {};
    const floatx4 zf = {};
    int sKrow = t >> 3, sKj = t & 7;
    int sVrow = t >> 4, sVj = t & 15;
    for (int k0 = 0; k0 < NS; k0 += 128) {
        __syncthreads();
#pragma unroll
        for (int it = 0; it < 4; it++) {
            int rowK = it * 32 + sKrow;
            int jK = sKj ^ (rowK & 7);
            GLD16(&QKV[(size_t)(b * NS + k0 + rowK) * N3 + 512 + h * NDH + jK * 8],
                  &Ks[(it * 256 + w * 64) * 8]);
            int rowV = it * 16 + sVrow;
            int jV = sVj ^ (rowV & 7);
            GLD16(&Vt[(size_t)(bh * NDH + rowV) * NS + k0 + jV * 8],
                  &Vs[(it * 256 + w * 64) * 8]);
        }
        __syncthreads();
#pragma unroll
        for (int kt = 0; kt < 4; kt++) {
            bf16x8 kfr[2][2];
#pragma unroll
            for (int tt = 0; tt < 2; tt++)
#pragma unroll
                for (int s = 0; s < 2; s++)
                    kfr[tt][s] = *(const bf16x8*)&Ks[(kt * 32 + tt * 16 + lr) * 64 +
                                                     ((s * 4 + lg) ^ (lr & 7)) * 8];
            bf16x8 vf[4];
#pragma unroll
            for (int nt = 0; nt < 4; nt++)
                vf[nt] = *(const bf16x8*)&Vs[(nt * 16 + lr) * 128 +
                                             ((kt * 4 + lg) ^ (lr & 7)) * 8];
#pragma unroll
            for (int n = 0; n < 2; n++) {
                // swapped scores: C[m=k'][n=q]
                floatx4 s0 = mfma16(kfr[0][0], qf[n][0], zf);
                s0 = mfma16(kfr[0][1], qf[n][1], s0);
                floatx4 s1 = mfma16(kfr[1][0], qf[n][0], zf);
                s1 = mfma16(kfr[1][1], qf[n][1], s1);
                float e0[4], e1[4];
#pragma unroll
                for (int r = 0; r < 4; r++) {
                    e0[r] = __expf(s0[r] * 0.125f);
                    e1[r] = __expf(s1[r] * 0.125f);
                }
                // in-register transpose to PV A-fragment layout
                unsigned A0 = pack2(e0[0], e0[1]);
                unsigned A1 = pack2(e0[2], e0[3]);
                unsigned B0 = pack2(e1[0], e1[1]);
                unsigned B1 = pack2(e1[2], e1[3]);
                plane32(A0, B0); plane16(A0, B0);
                plane32(A1, B1); plane16(A1, B1);
                union { unsigned u[4]; bf16x8 v; } af;
                af.u[0] = A0; af.u[1] = A1; af.u[2] = B0; af.u[3] = B1;
#pragma unroll
                for (int nt = 0; nt < 4; nt++)
                    oacc[n][nt] = mfma16(af.v, vf[nt], oacc[n][nt]);
            }
        }
    }
    // epilogue: y = out + x, plus BN channel partial sums
    float bs[4] = {}, bq2[4] = {};
#pragma unroll
    for (int n = 0; n < 2; n++)
#pragma unroll
        for (int nt = 0; nt < 4; nt++) {
            int d = nt * 16 + lr;
#pragma unroll
            for (int r = 0; r < 4; r++) {
                int q = q0 + w * 32 + n * 16 + lg * 4 + r;
                size_t idx = (size_t)(b * NS + q) * ND + h * NDH + d;
                float yv = oacc[n][nt][r] + x[idx];
                y[idx] = yv;
                bs[nt] += yv;
                bq2[nt] += yv * yv;
            }
        }
#pragma unroll
    for (int nt = 0; nt < 4; nt++) {
        float v = bs[nt], q2 = bq2[nt];
        v += __shfl_xor(v, 16); v += __shfl_xor(v, 32);
        q2 += __shfl_xor(q2, 16); q2 += __shfl_xor(q2, 32);
        if (lg == 0) {
            atomicAdd(&bnSum[h * NDH + nt * 16 + lr], v);
            atomicAdd(&bnSumSq[h * NDH + nt * 16 + lr], q2);
        }
    }
}

// ---------------- BN apply (in place on y) ----------------
__global__ void bn_apply(float* __restrict__ y, const float* __restrict__ bnSum,
                         const float* __restrict__ bnSumSq, const float* __restrict__ gamma,
                         const float* __restrict__ beta) {
    int i = (blockIdx.x * 256 + threadIdx.x) * 4;
    int c = i & 511;
    float4 v = *(float4*)&y[i];
    float vv[4] = {v.x, v.y, v.z, v.w};
    float out[4];
#pragma unroll
    for (int j = 0; j < 4; j++) {
        float mean = bnSum[c + j] * (1.f / 8192.f);
        float var = bnSumSq[c + j] * (1.f / 8192.f) - mean * mean;
        float rstd = rsqrtf(var + 1e-5f);
        out[j] = (vv[j] - mean) * rstd * gamma[c + j] + beta[c + j];
    }
    *(float4*)&y[i] = make_float4(out[0], out[1], out[2], out[3]);
}

extern "C" void kernel_launch(void* const* d_in, const int* in_sizes, int n_in,
                              void* d_out, int out_size, void* d_ws, size_t ws_size,
                              hipStream_t stream) {
    const float* x  = (const float*)d_in[0];
    const float* Wq = (const float*)d_in[1];
    const float* bq = (const float*)d_in[2];
    const float* Wk = (const float*)d_in[3];
    const float* bk = (const float*)d_in[4];
    const float* Wv = (const float*)d_in[5];
    const float* bv = (const float*)d_in[6];
    const float* gamma = (const float*)d_in[7];
    const float* beta  = (const float*)d_in[8];
    float* y = (float*)d_out;

    char* ws = (char*)d_ws;
    const size_t WB_OFF  = 0;
    const size_t QKV_OFF = 2u << 20;                          // 2 MiB
    const size_t VT_OFF  = QKV_OFF + (size_t)MROWS * N3 * 2;  // +24 MiB
    const size_t RC_OFF  = VT_OFF + (size_t)NBH * NDH * NS * 2;
    const size_t BN_OFF  = RC_OFF + (size_t)NBH * NS * 4;
    const size_t XB_OFF  = BN_OFF + (4u << 12);
    bf16*  Wb     = (bf16*)(ws + WB_OFF);
    bf16*  QKV    = (bf16*)(ws + QKV_OFF);
    bf16*  Vt     = (bf16*)(ws + VT_OFF);
    float* rc_arr = (float*)(ws + RC_OFF);
    float* bnSum  = (float*)(ws + BN_OFF);
    float* bnSumSq = bnSum + 512;
    bf16*  xb     = (bf16*)(ws + XB_OFF);

    zero_f32<<<4, 256, 0, stream>>>(bnSum, 1024);
    convert_x<<<2048, 256, 0, stream>>>(x, xb);
    convert_w<<<dim3(16, 16, 3), dim3(32, 8), 0, stream>>>(Wq, Wk, Wv, Wb);
    gemm1<<<dim3(64, 12), 256, 0, stream>>>(xb, Wb, bq, bk, bv, QKV);
    attn_colsum<<<dim3(64, 8), 256, 0, stream>>>(QKV, rc_arr);
    transpose_v<<<dim3(64, 16), 256, 0, stream>>>(QKV, rc_arr, Vt);
    attn_fused<<<dim3(64, 8), 256, 0, stream>>>(QKV, Vt, x, y, bnSum, bnSumSq);
    bn_apply<<<4096, 256, 0, stream>>>(y, bnSum, bnSumSq, gamma, beta);
}